// Round 15
// baseline (129.428 us; speedup 1.0000x reference)
//
#include <hip/hip_runtime.h>

// Problem constants (fixed by setup_inputs): B=4096, D=512, H=W=64, N=4096.
#define B_ROWS 4096
#define N_COLS 4096
#define DIM    512
#define LDK    1024   // row stride (elements) of split bf16 arrays [hi(512) | lo(512)]

typedef __attribute__((ext_vector_type(8))) short short8;
typedef __attribute__((ext_vector_type(4))) float floatx4;

// bf16 round-to-nearest-even split helpers (bit-exact, no API dependence)
__device__ __forceinline__ unsigned short f2bf_rn(float f) {
    unsigned u = __float_as_uint(f);
    u += 0x7fffu + ((u >> 16) & 1u);
    return (unsigned short)(u >> 16);
}
__device__ __forceinline__ float bf2f(unsigned short h) {
    return __uint_as_float(((unsigned)h) << 16);
}

// Monotone float->uint map; (key<<32)|idx gives u64 atomicMin argmin with
// smallest-index tie-break (matches numpy argmin semantics).
__device__ __forceinline__ unsigned long long pack_key(float v, int idx) {
    unsigned u = __float_as_uint(v);
    u = (u & 0x80000000u) ? ~u : (u | 0x80000000u);
    return ((unsigned long long)u << 32) | (unsigned)idx;
}

// Async global->LDS, 16B per lane. LDS dest is wave-uniform base + lane*16;
// global source address IS per-lane (m173).
__device__ __forceinline__ void async16(const unsigned short* g, unsigned short* l) {
    __builtin_amdgcn_global_load_lds(
        (__attribute__((address_space(1))) void*)g,
        (__attribute__((address_space(3))) void*)l, 16, 0, 0);
}

// One wave per row (4 rows/block): split fp32 row into bf16 hi/lo halves,
// compute exact fp32 ||row||^2, init packed argmin accumulators. (unchanged)
__global__ __launch_bounds__(256) void som_convert(
    const float* __restrict__ X, const float* __restrict__ Wt,
    unsigned short* __restrict__ Xc, unsigned short* __restrict__ Wc,
    float* __restrict__ x_sq, float* __restrict__ w_sq,
    unsigned long long* __restrict__ packed)
{
    int wave = threadIdx.x >> 6, lane = threadIdx.x & 63;
    int grow = blockIdx.x * 4 + wave;            // 0..8191
    bool isX = grow < B_ROWS;
    const float* src = isX ? (X + (size_t)grow * DIM)
                           : (Wt + (size_t)(grow - B_ROWS) * DIM);
    const float4* p4 = (const float4*)src;
    float4 a = p4[lane * 2], b = p4[lane * 2 + 1];
    float f[8] = {a.x, a.y, a.z, a.w, b.x, b.y, b.z, b.w};
    short8 hi, lo;
    float s = 0.f;
    #pragma unroll
    for (int t = 0; t < 8; ++t) {
        unsigned short h = f2bf_rn(f[t]);
        hi[t] = (short)h;
        lo[t] = (short)f2bf_rn(f[t] - bf2f(h));
        s = fmaf(f[t], f[t], s);
    }
    unsigned short* dst = (isX ? Xc + (size_t)grow * LDK
                               : Wc + (size_t)(grow - B_ROWS) * LDK) + lane * 8;
    *(short8*)(dst)       = hi;
    *(short8*)(dst + 512) = lo;
    #pragma unroll
    for (int off = 32; off >= 1; off >>= 1) s += __shfl_xor(s, off, 64);
    if (lane == 0) {
        if (isX) { x_sq[grow] = s; packed[grow] = ~0ull; }
        else     { w_sq[grow - B_ROWS] = s; }
    }
}

// ---------------------------------------------------------------------------
// Split-bf16 distance GEMM v15 (resubmit; R14 failed on container infra, not
// kernel): v14's in-wave-overlap schedule with the register cap bug fixed
// via __launch_bounds__(512, 1). v14's (512,2) promised 2 blocks/CU
// (impossible: 128KB LDS) and capped the allocator at 128 VGPR -> scratch
// spill (WRITE_SIZE 8->21.5MB). At the TRUE occupancy (1 block/CU, 2
// waves/SIMD) the budget is 256 VGPR; the +32-reg preload dbuf fits.
// Schedule (per K-step, one barrier):
//  - step OPENS with 16 MFMA on preloaded regs (a0,bh of this tile)
//  - remaining 16 ds_reads issue under clusters 1-3 (compiler interleaves
//    with fine lgkmcnt)
//  - mid-step {vmcnt(0); lgkm0; barrier}: slot[kt+1] globally staged
//    (issued a full step ago => drain ~instant) + all reads of slot[kt]
//    retired -> stage kt+2 over it
//  - tail: prefetch next step's cluster-1 operands from slot[kt+1], then
//    48 pure-reg MFMAs cover those reads
// Geometry: 256x256 block, 8 waves 2x4, 128x64/wave, BK=32, 128KB dbuf,
// rotation-coalesced staging (v7). Per-acc product order identical to v1
// (hh, ah*bl, al*bh; kt ascending) => bit-exact (v14 passed absmax 0.0).
// ---------------------------------------------------------------------------
#define MFMA16(AF, BF, I0)                                      \
    _Pragma("unroll")                                           \
    for (int i = 0; i < 4; ++i)                                 \
        _Pragma("unroll")                                       \
        for (int j = 0; j < 4; ++j)                             \
            acc[(I0) + i][j] = __builtin_amdgcn_mfma_f32_16x16x32_bf16( \
                AF[i], BF[j], acc[(I0) + i][j], 0, 0, 0);

// One K-step. SCUR/SNXT = LDS slot of tile KT / KT+1. A0C/BHC = preloaded
// cluster-1 operands of tile KT; A0N/BHN receive tile KT+1's.
#define DIST_STEP(KT, SCUR, SNXT, A0C, BHC, A0N, BHN)                          \
{                                                                              \
    const unsigned short* pA = &L[(SCUR) * 16384 + wr * 8192 + rdw8];          \
    const unsigned short* pB = &L[32768 + (SCUR) * 16384 + wc * 4096 + rdw8];  \
    short8 bl[4], al0[4], ah1[4], al1[4];                                      \
    /* c1 opens the step on preloaded regs; reads below overlap c1-c3 */       \
    __builtin_amdgcn_s_setprio(1);                                             \
    MFMA16(A0C, BHC, 0)                                                        \
    __builtin_amdgcn_s_setprio(0);                                             \
    _Pragma("unroll")                                                          \
    for (int j = 0; j < 4; ++j) bl[j]  = *(const short8*)(pB + j * 1024 + 512);\
    _Pragma("unroll")                                                          \
    for (int i = 0; i < 4; ++i) al0[i] = *(const short8*)(pA + i * 1024 + 512);\
    __builtin_amdgcn_s_setprio(1);                                             \
    MFMA16(A0C, bl, 0)                                                         \
    MFMA16(al0, BHC, 0)                                                        \
    __builtin_amdgcn_s_setprio(0);                                             \
    _Pragma("unroll")                                                          \
    for (int i = 0; i < 4; ++i) ah1[i] = *(const short8*)(pA + (4 + i) * 1024);\
    _Pragma("unroll")                                                          \
    for (int i = 0; i < 4; ++i) al1[i] = *(const short8*)(pA + (4 + i) * 1024 + 512); \
    /* mid-step gate: slot SNXT staged everywhere; slot SCUR reads retired */  \
    asm volatile("s_waitcnt vmcnt(0)" ::: "memory");                           \
    asm volatile("s_waitcnt lgkmcnt(0)" ::: "memory");                         \
    __builtin_amdgcn_s_barrier();                                              \
    asm volatile("" ::: "memory");                                             \
    if ((KT) < 14) {                                                           \
        unsigned short* RB = &L[32768 + (SCUR) * 16384];                       \
        unsigned short* RA = &L[(SCUR) * 16384];                               \
        const int k2o = ((KT) + 2) * 32;                                       \
        _Pragma("unroll")                                                      \
        for (int q = 0; q < 4; ++q) async16(gBq[q] + k2o, RB + (wave * 4 + q) * 512); \
        _Pragma("unroll")                                                      \
        for (int q = 0; q < 4; ++q) async16(gAq[q] + k2o, RA + (wave * 4 + q) * 512); \
    }                                                                          \
    if ((KT) < 15) {                                                           \
        const unsigned short* qA = &L[(SNXT) * 16384 + wr * 8192 + rdw8];      \
        const unsigned short* qB = &L[32768 + (SNXT) * 16384 + wc * 4096 + rdw8]; \
        _Pragma("unroll")                                                      \
        for (int i = 0; i < 4; ++i) A0N[i] = *(const short8*)(qA + i * 1024);  \
        _Pragma("unroll")                                                      \
        for (int j = 0; j < 4; ++j) BHN[j] = *(const short8*)(qB + j * 1024);  \
    }                                                                          \
    /* pure-reg tail: 48 MFMAs cover the prefetch reads above */               \
    __builtin_amdgcn_s_setprio(1);                                             \
    MFMA16(ah1, BHC, 4)                                                        \
    MFMA16(ah1, bl, 4)                                                         \
    MFMA16(al1, BHC, 4)                                                        \
    __builtin_amdgcn_s_setprio(0);                                             \
}

__global__ __launch_bounds__(512, 1) void som_dist_v15(
    const unsigned short* __restrict__ Xc, const unsigned short* __restrict__ Wc,
    const float* __restrict__ w_sq, unsigned long long* __restrict__ packed)
{
    __shared__ __align__(16) unsigned short L[65536];   // 128 KiB
    const int tid  = threadIdx.x;
    const int wave = tid >> 6, lane = tid & 63;
    const int quad = lane >> 4, t16 = lane & 15;
    const int wr = wave >> 2, wc = wave & 3;       // 2x4 wave grid, 128x64/wave
    const int bm = blockIdx.y, bn = blockIdx.x;

    // Cooperative staging: wave stages subtile-units s = wave*4+q (q=0..3)
    // of each region per K-tile (rsub = s>>1, h = s&1; LDS offset s*512).
    const int srow = lane >> 2;
    const int scol = ((((lane & 3) - ((lane >> 3) & 3)) & 3)) * 8;
    const unsigned short* gAq[4];
    const unsigned short* gBq[4];
    #pragma unroll
    for (int q = 0; q < 4; ++q) {
        const int s = wave * 4 + q, rsub = s >> 1, h = s & 1;
        gAq[q] = Xc + (size_t)(bm * 256 + rsub * 16 + srow) * LDK + h * 512 + scol;
        gBq[q] = Wc + (size_t)(bn * 256 + rsub * 16 + srow) * LDK + h * 512 + scol;
    }

    // Fragment read offset within a subtile-unit (rotation inverse, v7).
    const int rdw8 = (4 * t16 + ((quad + ((t16 >> 1) & 3)) & 3)) * 8;

    floatx4 acc[8][4];
    #pragma unroll
    for (int i = 0; i < 8; ++i)
        #pragma unroll
        for (int j = 0; j < 4; ++j) acc[i][j] = (floatx4){0.f, 0.f, 0.f, 0.f};

    // Prologue: stage tiles 0 and 1 (B then A per tile); gate tile 0 only
    // (tile 1's 8 loads stay in flight); preload cluster-1 of tile 0.
    #pragma unroll
    for (int t = 0; t < 2; ++t) {
        const int k0 = t * 32;
        unsigned short* RB = &L[32768 + t * 16384];
        unsigned short* RA = &L[t * 16384];
        #pragma unroll
        for (int q = 0; q < 4; ++q) async16(gBq[q] + k0, RB + (wave * 4 + q) * 512);
        #pragma unroll
        for (int q = 0; q < 4; ++q) async16(gAq[q] + k0, RA + (wave * 4 + q) * 512);
    }
    asm volatile("s_waitcnt vmcnt(8)" ::: "memory");
    __builtin_amdgcn_s_barrier();
    asm volatile("" ::: "memory");

    short8 a0A[4], bhA[4], a0B[4], bhB[4];
    {
        const unsigned short* pA = &L[wr * 8192 + rdw8];
        const unsigned short* pB = &L[32768 + wc * 4096 + rdw8];
        #pragma unroll
        for (int i = 0; i < 4; ++i) a0A[i] = *(const short8*)(pA + i * 1024);
        #pragma unroll
        for (int j = 0; j < 4; ++j) bhA[j] = *(const short8*)(pB + j * 1024);
    }

    #pragma unroll 1
    for (int k2 = 0; k2 < 8; ++k2) {
        const int kt = k2 * 2;
        DIST_STEP(kt,     0, 1, a0A, bhA, a0B, bhB)
        DIST_STEP(kt + 1, 1, 0, a0B, bhB, a0A, bhA)
    }

    // Epilogue: val = w_sq - 2*dot (x_sq is per-row constant, irrelevant to
    // argmin). C/D layout: col = t16, row = quad*4 + reg  [m89/m91].
    const int col0 = bn * 256 + wc * 64 + t16;
    float wq[4];
    #pragma unroll
    for (int j = 0; j < 4; ++j) wq[j] = w_sq[col0 + j * 16];
    const int row_base = bm * 256 + wr * 128 + quad * 4;
    #pragma unroll
    for (int i = 0; i < 8; ++i) {
        #pragma unroll
        for (int r = 0; r < 4; ++r) {
            unsigned long long best = ~0ull;
            #pragma unroll
            for (int j = 0; j < 4; ++j) {
                float val = fmaf(-2.f, acc[i][j][r], wq[j]);
                unsigned long long key = pack_key(val, col0 + j * 16);
                best = (key < best) ? key : best;
            }
            #pragma unroll
            for (int m = 1; m <= 8; m <<= 1) {     // reduce 16-lane col group
                unsigned long long o = __shfl_xor(best, m, 64);
                best = (o < best) ? o : best;
            }
            if (t16 == 0)
                atomicMin(&packed[row_base + i * 16 + r], best);
        }
    }
}

// Unpack argmin, qe = sqrt(max(||x||^2 + val, 0)).
// d_out: bmu_indices (4096 x 2) flat, then qe (4096), all float. (unchanged)
__global__ __launch_bounds__(256) void som_finalize(
    const unsigned long long* __restrict__ packed,
    const float* __restrict__ x_sq, float* __restrict__ out)
{
    int b = blockIdx.x * 256 + threadIdx.x;  // 0..4095
    unsigned long long p = packed[b];
    unsigned idx = (unsigned)(p & 0xffffffffull);
    unsigned key = (unsigned)(p >> 32);
    unsigned u = (key & 0x80000000u) ? (key & 0x7fffffffu) : ~key;
    float val = __uint_as_float(u);
    float sq = fmaxf(x_sq[b] + val, 0.f);
    out[2 * b]     = (float)(idx >> 6);   // y = idx / 64
    out[2 * b + 1] = (float)(idx & 63);   // x = idx % 64
    out[2 * B_ROWS + b] = sqrtf(sq);
}

extern "C" void kernel_launch(void* const* d_in, const int* in_sizes, int n_in,
                              void* d_out, int out_size, void* d_ws, size_t ws_size,
                              hipStream_t stream) {
    const float* X  = (const float*)d_in[0];   // (4096, 512)
    const float* Wt = (const float*)d_in[1];   // (64, 64, 512) -> (4096, 512)
    float* out = (float*)d_out;

    // ws layout: [0,32K) packed u64[4096]; [32K,48K) x_sq; [48K,64K) w_sq;
    // [64K, 64K+8M) Xc bf16 split; [64K+8M, 64K+16M) Wc bf16 split.
    unsigned long long* packed = (unsigned long long*)d_ws;
    float* x_sq = (float*)((char*)d_ws + (32 << 10));
    float* w_sq = (float*)((char*)d_ws + (48 << 10));
    unsigned short* Xc = (unsigned short*)((char*)d_ws + (64 << 10));
    unsigned short* Wc = (unsigned short*)((char*)d_ws + (64 << 10) + ((size_t)B_ROWS * LDK * 2));

    som_convert<<<dim3((B_ROWS + N_COLS) / 4), dim3(256), 0, stream>>>(
        X, Wt, Xc, Wc, x_sq, w_sq, packed);
    som_dist_v15<<<dim3(N_COLS / 256, B_ROWS / 256), dim3(512), 0, stream>>>(
        Xc, Wc, w_sq, packed);
    som_finalize<<<dim3(B_ROWS / 256), dim3(256), 0, stream>>>(packed, x_sq, out);
}

// Round 16
// 114.171 us; speedup vs baseline: 1.1336x; 1.1336x over previous
//
#include <hip/hip_runtime.h>

// Problem constants (fixed by setup_inputs): B=4096, D=512, H=W=64, N=4096.
#define B_ROWS 4096
#define N_COLS 4096
#define DIM    512
#define LDK    1024   // row stride (elements) of split bf16 arrays [hi(512) | lo(512)]

typedef __attribute__((ext_vector_type(8))) short short8;
typedef __attribute__((ext_vector_type(4))) float floatx4;

// bf16 round-to-nearest-even split helpers (bit-exact, no API dependence)
__device__ __forceinline__ unsigned short f2bf_rn(float f) {
    unsigned u = __float_as_uint(f);
    u += 0x7fffu + ((u >> 16) & 1u);
    return (unsigned short)(u >> 16);
}
__device__ __forceinline__ float bf2f(unsigned short h) {
    return __uint_as_float(((unsigned)h) << 16);
}

// Monotone float->uint map; (key<<32)|idx gives u64 atomicMin argmin with
// smallest-index tie-break (matches numpy argmin semantics).
__device__ __forceinline__ unsigned long long pack_key(float v, int idx) {
    unsigned u = __float_as_uint(v);
    u = (u & 0x80000000u) ? ~u : (u | 0x80000000u);
    return ((unsigned long long)u << 32) | (unsigned)idx;
}

// Async global->LDS, 16B per lane. LDS dest is wave-uniform base + lane*16;
// global source address IS per-lane (m173).
__device__ __forceinline__ void async16(const unsigned short* g, unsigned short* l) {
    __builtin_amdgcn_global_load_lds(
        (__attribute__((address_space(1))) void*)g,
        (__attribute__((address_space(3))) void*)l, 16, 0, 0);
}

// One wave per row (4 rows/block): split fp32 row into bf16 hi/lo halves,
// compute exact fp32 ||row||^2, init packed argmin accumulators. (unchanged)
__global__ __launch_bounds__(256) void som_convert(
    const float* __restrict__ X, const float* __restrict__ Wt,
    unsigned short* __restrict__ Xc, unsigned short* __restrict__ Wc,
    float* __restrict__ x_sq, float* __restrict__ w_sq,
    unsigned long long* __restrict__ packed)
{
    int wave = threadIdx.x >> 6, lane = threadIdx.x & 63;
    int grow = blockIdx.x * 4 + wave;            // 0..8191
    bool isX = grow < B_ROWS;
    const float* src = isX ? (X + (size_t)grow * DIM)
                           : (Wt + (size_t)(grow - B_ROWS) * DIM);
    const float4* p4 = (const float4*)src;
    float4 a = p4[lane * 2], b = p4[lane * 2 + 1];
    float f[8] = {a.x, a.y, a.z, a.w, b.x, b.y, b.z, b.w};
    short8 hi, lo;
    float s = 0.f;
    #pragma unroll
    for (int t = 0; t < 8; ++t) {
        unsigned short h = f2bf_rn(f[t]);
        hi[t] = (short)h;
        lo[t] = (short)f2bf_rn(f[t] - bf2f(h));
        s = fmaf(f[t], f[t], s);
    }
    unsigned short* dst = (isX ? Xc + (size_t)grow * LDK
                               : Wc + (size_t)(grow - B_ROWS) * LDK) + lane * 8;
    *(short8*)(dst)       = hi;
    *(short8*)(dst + 512) = lo;
    #pragma unroll
    for (int off = 32; off >= 1; off >>= 1) s += __shfl_xor(s, off, 64);
    if (lane == 0) {
        if (isX) { x_sq[grow] = s; packed[grow] = ~0ull; }
        else     { w_sq[grow - B_ROWS] = s; }
    }
}

// ---------------------------------------------------------------------------
// Split-bf16 distance GEMM v16: the in-wave-overlap schedule on a REGISTER
// DIET that fits the unified 256-reg/wave budget at 2 waves/SIMD
// (v14/v15 spilled: acc 128 AGPR + ~160 VGPR > 256; here ~120 V + 128 A).
//  - preload only bh of the next tile (bhA/bhB, 32 regs; a0 preload dropped)
//  - NO top-of-step gate/barrier: slot[kt] was vmcnt(0)-proven at mid-step
//    kt-1; all reads of slot[kt] precede kt's mid barrier; staging over
//    slot[kt] (tile kt+2) happens only after that barrier. ONE barrier/step.
//  - mid-step {vmcnt(0); lgkm0; barrier}: tile kt+1 staged everywhere
//    (issued a full step ago) + all slot[kt] reads retired
//  - tail: stage kt+2, prefetch bh(kt+1) from slot[kt+1], 48 pure-reg MFMAs
//  - pointer diet: staging addresses = uniform SGPR bases (readfirstlane'd
//    wave) + one per-lane 32-bit offset -> saddr-form loads, ~14 VGPR saved
// Geometry: 256x256 block, 8 waves 2x4, 128x64/wave, BK=32, 128KB dbuf,
// rotation-coalesced staging (v7). Per-acc product order identical to v1
// (hh, ah*bl, al*bh; kt ascending) => bit-exact.
// ---------------------------------------------------------------------------
#define MFMA16(AF, BF, I0)                                      \
    _Pragma("unroll")                                           \
    for (int i = 0; i < 4; ++i)                                 \
        _Pragma("unroll")                                       \
        for (int j = 0; j < 4; ++j)                             \
            acc[(I0) + i][j] = __builtin_amdgcn_mfma_f32_16x16x32_bf16( \
                AF[i], BF[j], acc[(I0) + i][j], 0, 0, 0);

// One K-step. SCUR/SNXT = LDS slot of tile KT / KT+1. BHC = preloaded bh of
// tile KT; BHN receives tile KT+1's bh.
#define DIST_STEP(KT, SCUR, SNXT, BHC, BHN)                                    \
{                                                                              \
    const unsigned short* pA = &L[(SCUR) * 16384 + wr * 8192 + rdw8];          \
    const unsigned short* pB = &L[32768 + (SCUR) * 16384 + wc * 4096 + rdw8];  \
    short8 ah0[4], bl[4], al0[4], ah1[4], al1[4];                              \
    /* no top gate: slot SCUR proven at prev mid barrier; bh preloaded */      \
    _Pragma("unroll")                                                          \
    for (int i = 0; i < 4; ++i) ah0[i] = *(const short8*)(pA + i * 1024);      \
    __builtin_amdgcn_s_setprio(1);                                             \
    MFMA16(ah0, BHC, 0)                                                        \
    __builtin_amdgcn_s_setprio(0);                                             \
    _Pragma("unroll")                                                          \
    for (int j = 0; j < 4; ++j) bl[j]  = *(const short8*)(pB + j * 1024 + 512);\
    __builtin_amdgcn_s_setprio(1);                                             \
    MFMA16(ah0, bl, 0)                                                         \
    __builtin_amdgcn_s_setprio(0);                                             \
    _Pragma("unroll")                                                          \
    for (int i = 0; i < 4; ++i) al0[i] = *(const short8*)(pA + i * 1024 + 512);\
    __builtin_amdgcn_s_setprio(1);                                             \
    MFMA16(al0, BHC, 0)                                                        \
    __builtin_amdgcn_s_setprio(0);                                             \
    _Pragma("unroll")                                                          \
    for (int i = 0; i < 4; ++i) ah1[i] = *(const short8*)(pA + (4 + i) * 1024);\
    _Pragma("unroll")                                                          \
    for (int i = 0; i < 4; ++i) al1[i] = *(const short8*)(pA + (4 + i) * 1024 + 512); \
    /* mid-step gate: tile KT+1 staged everywhere; slot SCUR reads retired */  \
    asm volatile("s_waitcnt vmcnt(0)" ::: "memory");                           \
    asm volatile("s_waitcnt lgkmcnt(0)" ::: "memory");                         \
    __builtin_amdgcn_s_barrier();                                              \
    asm volatile("" ::: "memory");                                             \
    if ((KT) < 14) {                                                           \
        const int k2o = ((KT) + 2) * 32;                                       \
        _Pragma("unroll")                                                      \
        for (int q = 0; q < 4; ++q) {                                          \
            const int s = wv4 + q, rsub = s >> 1, h = s & 1;                   \
            async16(gBbase + (size_t)(rsub * 16) * LDK + h * 512 + k2o + pl,   \
                    &L[32768 + (SCUR) * 16384 + s * 512]);                     \
            async16(gAbase + (size_t)(rsub * 16) * LDK + h * 512 + k2o + pl,   \
                    &L[(SCUR) * 16384 + s * 512]);                             \
        }                                                                      \
    }                                                                          \
    if ((KT) < 15) {                                                           \
        const unsigned short* qB = &L[32768 + (SNXT) * 16384 + wc * 4096 + rdw8]; \
        _Pragma("unroll")                                                      \
        for (int j = 0; j < 4; ++j) BHN[j] = *(const short8*)(qB + j * 1024);  \
    }                                                                          \
    /* pure-reg tail: 48 MFMAs cover the bh prefetch above */                  \
    __builtin_amdgcn_s_setprio(1);                                             \
    MFMA16(ah1, BHC, 4)                                                        \
    MFMA16(ah1, bl, 4)                                                         \
    MFMA16(al1, BHC, 4)                                                        \
    __builtin_amdgcn_s_setprio(0);                                             \
}

__global__ __launch_bounds__(512, 1) void som_dist_v16(
    const unsigned short* __restrict__ Xc, const unsigned short* __restrict__ Wc,
    const float* __restrict__ w_sq, unsigned long long* __restrict__ packed)
{
    __shared__ __align__(16) unsigned short L[65536];   // 128 KiB
    const int tid  = threadIdx.x;
    const int wave = tid >> 6, lane = tid & 63;
    const int quad = lane >> 4, t16 = lane & 15;
    const int wr = wave >> 2, wc = wave & 3;       // 2x4 wave grid, 128x64/wave
    const int bm = blockIdx.y, bn = blockIdx.x;

    // Staging addressing: uniform SGPR bases + single per-lane offset.
    const int wv  = __builtin_amdgcn_readfirstlane(wave);
    const int wv4 = wv * 4;
    const int srow = lane >> 2;
    const int scol = ((((lane & 3) - ((lane >> 3) & 3)) & 3)) * 8;
    const unsigned pl = (unsigned)(srow * LDK + scol);            // per-lane
    const unsigned short* const gAbase = Xc + (size_t)(bm * 256) * LDK;
    const unsigned short* const gBbase = Wc + (size_t)(bn * 256) * LDK;

    // Fragment read offset within a subtile-unit (rotation inverse, v7).
    const int rdw8 = (4 * t16 + ((quad + ((t16 >> 1) & 3)) & 3)) * 8;

    floatx4 acc[8][4];
    #pragma unroll
    for (int i = 0; i < 8; ++i)
        #pragma unroll
        for (int j = 0; j < 4; ++j) acc[i][j] = (floatx4){0.f, 0.f, 0.f, 0.f};

    // Prologue: stage tiles 0 and 1 (B then A per tile; 16 loads in flight);
    // gate tile 0 only (vmcnt(8): tile 1's 8 stay in flight); preload bh(0).
    #pragma unroll
    for (int t = 0; t < 2; ++t) {
        const int k0 = t * 32;
        #pragma unroll
        for (int q = 0; q < 4; ++q) {
            const int s = wv4 + q, rsub = s >> 1, h = s & 1;
            async16(gBbase + (size_t)(rsub * 16) * LDK + h * 512 + k0 + pl,
                    &L[32768 + t * 16384 + s * 512]);
            async16(gAbase + (size_t)(rsub * 16) * LDK + h * 512 + k0 + pl,
                    &L[t * 16384 + s * 512]);
        }
    }
    asm volatile("s_waitcnt vmcnt(8)" ::: "memory");
    __builtin_amdgcn_s_barrier();
    asm volatile("" ::: "memory");

    short8 bhA[4], bhB[4];
    {
        const unsigned short* qB = &L[32768 + wc * 4096 + rdw8];
        #pragma unroll
        for (int j = 0; j < 4; ++j) bhA[j] = *(const short8*)(qB + j * 1024);
    }

    #pragma unroll 1
    for (int k2 = 0; k2 < 8; ++k2) {
        const int kt = k2 * 2;
        DIST_STEP(kt,     0, 1, bhA, bhB)
        DIST_STEP(kt + 1, 1, 0, bhB, bhA)
    }

    // Epilogue: val = w_sq - 2*dot (x_sq is per-row constant, irrelevant to
    // argmin). C/D layout: col = t16, row = quad*4 + reg  [m89/m91].
    const int col0 = bn * 256 + wc * 64 + t16;
    float wq[4];
    #pragma unroll
    for (int j = 0; j < 4; ++j) wq[j] = w_sq[col0 + j * 16];
    const int row_base = bm * 256 + wr * 128 + quad * 4;
    #pragma unroll
    for (int i = 0; i < 8; ++i) {
        #pragma unroll
        for (int r = 0; r < 4; ++r) {
            unsigned long long best = ~0ull;
            #pragma unroll
            for (int j = 0; j < 4; ++j) {
                float val = fmaf(-2.f, acc[i][j][r], wq[j]);
                unsigned long long key = pack_key(val, col0 + j * 16);
                best = (key < best) ? key : best;
            }
            #pragma unroll
            for (int m = 1; m <= 8; m <<= 1) {     // reduce 16-lane col group
                unsigned long long o = __shfl_xor(best, m, 64);
                best = (o < best) ? o : best;
            }
            if (t16 == 0)
                atomicMin(&packed[row_base + i * 16 + r], best);
        }
    }
}

// Unpack argmin, qe = sqrt(max(||x||^2 + val, 0)).
// d_out: bmu_indices (4096 x 2) flat, then qe (4096), all float. (unchanged)
__global__ __launch_bounds__(256) void som_finalize(
    const unsigned long long* __restrict__ packed,
    const float* __restrict__ x_sq, float* __restrict__ out)
{
    int b = blockIdx.x * 256 + threadIdx.x;  // 0..4095
    unsigned long long p = packed[b];
    unsigned idx = (unsigned)(p & 0xffffffffull);
    unsigned key = (unsigned)(p >> 32);
    unsigned u = (key & 0x80000000u) ? (key & 0x7fffffffu) : ~key;
    float val = __uint_as_float(u);
    float sq = fmaxf(x_sq[b] + val, 0.f);
    out[2 * b]     = (float)(idx >> 6);   // y = idx / 64
    out[2 * b + 1] = (float)(idx & 63);   // x = idx % 64
    out[2 * B_ROWS + b] = sqrtf(sq);
}

extern "C" void kernel_launch(void* const* d_in, const int* in_sizes, int n_in,
                              void* d_out, int out_size, void* d_ws, size_t ws_size,
                              hipStream_t stream) {
    const float* X  = (const float*)d_in[0];   // (4096, 512)
    const float* Wt = (const float*)d_in[1];   // (64, 64, 512) -> (4096, 512)
    float* out = (float*)d_out;

    // ws layout: [0,32K) packed u64[4096]; [32K,48K) x_sq; [48K,64K) w_sq;
    // [64K, 64K+8M) Xc bf16 split; [64K+8M, 64K+16M) Wc bf16 split.
    unsigned long long* packed = (unsigned long long*)d_ws;
    float* x_sq = (float*)((char*)d_ws + (32 << 10));
    float* w_sq = (float*)((char*)d_ws + (48 << 10));
    unsigned short* Xc = (unsigned short*)((char*)d_ws + (64 << 10));
    unsigned short* Wc = (unsigned short*)((char*)d_ws + (64 << 10) + ((size_t)B_ROWS * LDK * 2));

    som_convert<<<dim3((B_ROWS + N_COLS) / 4), dim3(256), 0, stream>>>(
        X, Wt, Xc, Wc, x_sq, w_sq, packed);
    som_dist_v16<<<dim3(N_COLS / 256, B_ROWS / 256), dim3(512), 0, stream>>>(
        Xc, Wc, w_sq, packed);
    som_finalize<<<dim3(B_ROWS / 256), dim3(256), 0, stream>>>(packed, x_sq, out);
}